// Round 11
// baseline (276.627 us; speedup 1.0000x reference)
//
#include <hip/hip_runtime.h>
#include <cmath>

#define EPSV 1e-8f

typedef __bf16 bf16_t;
typedef __bf16 bf16x8 __attribute__((ext_vector_type(8)));
typedef float f32x4 __attribute__((ext_vector_type(4)));

__device__ __forceinline__ void gload16(const void* g, void* l) {
    __builtin_amdgcn_global_load_lds(
        (const __attribute__((address_space(1))) void*)g,
        (__attribute__((address_space(3))) void*)l, 16, 0, 0);
}

// ---- 128x128 MFMA GEMM (m97 structure: linear LDS, gload_lds, 2-barrier) --
// A: M x K bf16 row-major, BT: N x K bf16. C = [relu](A@B + bias) bf16.
// 256 thr = 4 waves, wave tile 64x64 (4x4 frags of 16x16x32).
// + XCD slab swizzle (L2 reuse of A panels), + LDS-staged coalesced epilogue.
template<bool RELU>
__global__ __launch_bounds__(256) void gemm128(
    const bf16_t* __restrict__ A, const bf16_t* __restrict__ BT,
    const float* __restrict__ bias, bf16_t* __restrict__ C,
    int N, int K, int nbx)
{
    __shared__ __align__(16) bf16_t As[128 * 32];   // 8 KB, [m][k] linear
    __shared__ __align__(16) bf16_t Bs[128 * 32];   // 8 KB, [n][k] linear
    __shared__ __align__(16) char   eb[32768];      // epilogue staging

    const int t    = threadIdx.x;
    const int lane = t & 63;
    const int w    = t >> 6;
    const int wm   = (w >> 1) << 6;
    const int wn   = (w & 1) << 6;

    // bijective XCD swizzle: each XCD gets a contiguous slab of tile-rows
    const int nwg = gridDim.x;
    int bid = blockIdx.x;
    int swz = ((nwg & 7) == 0) ? ((bid & 7) * (nwg >> 3) + (bid >> 3)) : bid;
    const int bx = swz % nbx, by = swz / nbx;
    const int m0 = by << 7, n0 = bx << 7;

    const int srow  = t >> 2;
    const int skoff = (t & 3) << 3;

    const bf16_t* Ap = A  + (size_t)(m0 + srow) * K + skoff;
    const bf16_t* Bp = BT + (size_t)(n0 + srow) * K + skoff;
    const size_t rstep = (size_t)64 * K;

    bf16_t* lA0 = As + ((w << 6)      ) * 8;
    bf16_t* lA1 = As + ((w << 6) + 256) * 8;
    bf16_t* lB0 = Bs + ((w << 6)      ) * 8;
    bf16_t* lB1 = Bs + ((w << 6) + 256) * 8;

    f32x4 acc[4][4];
#pragma unroll
    for (int i = 0; i < 4; ++i)
#pragma unroll
        for (int j = 0; j < 4; ++j) acc[i][j] = (f32x4){0.f, 0.f, 0.f, 0.f};

    const int r16  = lane & 15;
    const int u16  = lane >> 4;
    const int kblk = u16 << 3;

    for (int k0 = 0; k0 < K; k0 += 32) {
        __syncthreads();
        gload16(Ap + k0,         lA0);
        gload16(Ap + rstep + k0, lA1);
        gload16(Bp + k0,         lB0);
        gload16(Bp + rstep + k0, lB1);
        __syncthreads();

        bf16x8 af[4], bfr[4];
#pragma unroll
        for (int i = 0; i < 4; ++i) {
            af[i]  = *(const bf16x8*)&As[(wm + (i << 4) + r16) * 32 + kblk];
            bfr[i] = *(const bf16x8*)&Bs[(wn + (i << 4) + r16) * 32 + kblk];
        }
#pragma unroll
        for (int i = 0; i < 4; ++i)
#pragma unroll
            for (int j = 0; j < 4; ++j)
                acc[i][j] = __builtin_amdgcn_mfma_f32_16x16x32_bf16(af[i], bfr[j], acc[i][j], 0, 0, 0);
    }

    // ---- epilogue: bias+relu -> eb (bf16[128][128], 16B-XOR swizzled) ----
    // byte(row,col) = row*256 + ((col*2) ^ ((row&15)<<4)); bijective per row.
#pragma unroll
    for (int j = 0; j < 4; ++j) {
        const int col = wn + (j << 4) + r16;
        const float bv = bias[n0 + col];
#pragma unroll
        for (int i = 0; i < 4; ++i) {
            const int rb = wm + (i << 4) + (u16 << 2);
#pragma unroll
            for (int r = 0; r < 4; ++r) {
                float v = acc[i][j][r] + bv;
                if (RELU) v = fmaxf(v, 0.f);
                const int row = rb + r;
                *(bf16_t*)(eb + row * 256 + ((col << 1) ^ ((row & 15) << 4))) = (bf16_t)v;
            }
        }
    }
    __syncthreads();
    // coalesced stores: 16 lanes x 16B = one 256B row per lane-group
#pragma unroll
    for (int rp = 0; rp < 8; ++rp) {
        const int row = (rp << 4) + (t >> 4);
        const int c   = t & 15;
        bf16x8 v = *(const bf16x8*)(eb + row * 256 + ((c << 4) ^ ((row & 15) << 4)));
        *(bf16x8*)(C + (size_t)(m0 + row) * N + n0 + (c << 3)) = v;
    }
}

// ---- fused head: hd = h2 @ Whead + bhead (128x128 tile in LDS), then ------
// probability pipeline + per-block loss partial. One block per 128 rows.
__global__ __launch_bounds__(256) void head_fused(
    const bf16_t* __restrict__ A /*h2 slice*/, const bf16_t* __restrict__ BT /*WhT 128x512*/,
    const float* __restrict__ bias /*bhead*/, const int* __restrict__ data,
    float* __restrict__ probs_out, float* __restrict__ partials,
    int K, int row0)
{
    __shared__ __align__(16) bf16_t As[128 * 32];   // 8 KB
    __shared__ __align__(16) bf16_t Bs[128 * 32];   // 8 KB
    __shared__ float hdl[128 * 128];                // 64 KB

    const int t    = threadIdx.x;
    const int lane = t & 63;
    const int w    = t >> 6;
    const int wm   = (w >> 1) << 6;
    const int wn   = (w & 1) << 6;
    const int m0l  = blockIdx.x << 7;               // slice-local row base

    const int srow  = t >> 2;
    const int skoff = (t & 3) << 3;

    const bf16_t* Ap = A  + (size_t)(m0l + srow) * K + skoff;
    const bf16_t* Bp = BT + (size_t)srow * K + skoff;   // n0 = 0 (N=128)
    const size_t rstep = (size_t)64 * K;

    bf16_t* lA0 = As + ((w << 6)      ) * 8;
    bf16_t* lA1 = As + ((w << 6) + 256) * 8;
    bf16_t* lB0 = Bs + ((w << 6)      ) * 8;
    bf16_t* lB1 = Bs + ((w << 6) + 256) * 8;

    f32x4 acc[4][4];
#pragma unroll
    for (int i = 0; i < 4; ++i)
#pragma unroll
        for (int j = 0; j < 4; ++j) acc[i][j] = (f32x4){0.f, 0.f, 0.f, 0.f};

    const int r16  = lane & 15;
    const int u16  = lane >> 4;
    const int kblk = u16 << 3;

    for (int k0 = 0; k0 < K; k0 += 32) {
        __syncthreads();
        gload16(Ap + k0,         lA0);
        gload16(Ap + rstep + k0, lA1);
        gload16(Bp + k0,         lB0);
        gload16(Bp + rstep + k0, lB1);
        __syncthreads();

        bf16x8 af[4], bfr[4];
#pragma unroll
        for (int i = 0; i < 4; ++i) {
            af[i]  = *(const bf16x8*)&As[(wm + (i << 4) + r16) * 32 + kblk];
            bfr[i] = *(const bf16x8*)&Bs[(wn + (i << 4) + r16) * 32 + kblk];
        }
#pragma unroll
        for (int i = 0; i < 4; ++i)
#pragma unroll
            for (int j = 0; j < 4; ++j)
                acc[i][j] = __builtin_amdgcn_mfma_f32_16x16x32_bf16(af[i], bfr[j], acc[i][j], 0, 0, 0);
    }

    // hd tile -> LDS (f32), bias added
#pragma unroll
    for (int j = 0; j < 4; ++j) {
        const int col = wn + (j << 4) + r16;
        const float bv = bias[col];
#pragma unroll
        for (int i = 0; i < 4; ++i) {
            const int rb = wm + (i << 4) + (u16 << 2);
#pragma unroll
            for (int r = 0; r < 4; ++r)
                hdl[(rb + r) * 128 + col] = acc[i][j][r] + bv;
        }
    }
    __syncthreads();

    // probability pipeline: 8 (row,item) pairs per thread
    float lsum = 0.f;
    const int item = t & 15;
    const int cp   = 4 + (item & 3);
#pragma unroll
    for (int p = 0; p < 8; ++p) {
        const int row = (p << 4) + (t >> 4);
        const float* h = hdl + row * 128;
        const size_t grow = (size_t)row0 + m0l + row;

        const float f = h[item];
        float cumP[7];
        float cum = 0.f;
#pragma unroll
        for (int c = 0; c < 7; ++c) {
            if (c < cp) {
                float e = fmaxf(expf(h[16 + item * 7 + c]), EPSV);
                cum += e;
                float s = 1.f / (1.f + expf(f - cum));
                cumP[c] = fminf(fmaxf(s, EPSV), 1.f - EPSV);
            } else {
                cumP[c] = 0.f;
            }
        }
        float probs[8];
#pragma unroll
        for (int k = 0; k < 8; ++k) {
            float v;
            if (k < cp)       v = (k == 0) ? cumP[0] : (cumP[k] - cumP[k - 1]);
            else if (k == cp) v = 1.f - cumP[cp - 1];
            else              v = 1.f;
            probs[k] = fminf(fmaxf(v, EPSV), 1.f - EPSV);
        }
        float* dst = probs_out + (grow * 16 + item) * 8;
#pragma unroll
        for (int k = 0; k < 8; ++k) dst[k] = probs[k];

        const int d = data[grow * 16 + item];
        float g = probs[0];
#pragma unroll
        for (int k = 1; k < 8; ++k) g = (d == k) ? probs[k] : g;
        lsum += -logf(g);
    }

    // block loss reduction (reuse As as f32 scratch — all LDS reads long done)
    __syncthreads();
    float* red = (float*)As;
    red[t] = lsum;
    __syncthreads();
#pragma unroll
    for (int s2 = 128; s2 > 0; s2 >>= 1) {
        if (t < s2) red[t] += red[t + s2];
        __syncthreads();
    }
    if (t == 0) partials[(row0 >> 7) + blockIdx.x] = red[0];
}

// ---------------- fp32 -> bf16 conversion (8 elems/thread) ----------------
__global__ __launch_bounds__(256) void convert_x(
    const float* __restrict__ in, bf16_t* __restrict__ out, int n8)
{
    int i = blockIdx.x * 256 + threadIdx.x;
    if (i >= n8) return;
    const float4* p = (const float4*)in;
    float4 a = p[2 * i], b = p[2 * i + 1];
    bf16x8 v;
    v[0] = (bf16_t)a.x; v[1] = (bf16_t)a.y; v[2] = (bf16_t)a.z; v[3] = (bf16_t)a.w;
    v[4] = (bf16_t)b.x; v[5] = (bf16_t)b.y; v[6] = (bf16_t)b.z; v[7] = (bf16_t)b.w;
    ((bf16x8*)out)[i] = v;
}

// ---------------- transpose weight K x N fp32 -> N x K bf16 ----------------
__global__ __launch_bounds__(256) void transpose_w(
    const float* __restrict__ in, bf16_t* __restrict__ out,
    int kshift, int N, int total)
{
    int idx = blockIdx.x * 256 + threadIdx.x;
    if (idx >= total) return;
    int n = idx >> kshift;
    int k = idx & ((1 << kshift) - 1);
    out[idx] = (bf16_t)in[(size_t)k * N + n];
}

// ---------------- pack head: WheadT (128 x 512) bf16 + bhead (128) f32 -----
__global__ __launch_bounds__(256) void pack_head(
    const float* __restrict__ Wf, const float* __restrict__ bfv,
    const float* __restrict__ Wk, const float* __restrict__ bk,
    bf16_t* __restrict__ WhT, float* __restrict__ bhead)
{
    int idx = blockIdx.x * 256 + threadIdx.x;  // 0..65535
    int n = idx >> 9;      // 0..127
    int k = idx & 511;
    float v;
    if (n < 16) {
        v = Wf[k * 16 + n];
    } else {
        int m = n - 16;
        int i = m / 7, c = m % 7;
        v = Wk[(size_t)i * 3584 + (size_t)k * 7 + c];
    }
    WhT[idx] = (bf16_t)v;
    if (idx < 128) bhead[idx] = (idx < 16) ? bfv[idx] : bk[idx - 16];
}

__global__ __launch_bounds__(256) void reduce_loss(
    const float* __restrict__ partials, int n, float* __restrict__ out, float scale)
{
    __shared__ float red[256];
    float s = 0.f;
    for (int i = threadIdx.x; i < n; i += 256) s += partials[i];
    red[threadIdx.x] = s;
    __syncthreads();
    for (int k = 128; k > 0; k >>= 1) {
        if (threadIdx.x < k) red[threadIdx.x] += red[threadIdx.x + k];
        __syncthreads();
    }
    if (threadIdx.x == 0) out[0] = red[0] * scale;
}

extern "C" void kernel_launch(void* const* d_in, const int* in_sizes, int n_in,
                              void* d_out, int out_size, void* d_ws, size_t ws_size,
                              hipStream_t stream)
{
    const float* x   = (const float*)d_in[0];
    const int*   dat = (const int*)d_in[1];
    const float* W1  = (const float*)d_in[2];
    const float* b1  = (const float*)d_in[3];
    const float* W2  = (const float*)d_in[4];
    const float* b2  = (const float*)d_in[5];
    const float* Wf  = (const float*)d_in[6];
    const float* bfv = (const float*)d_in[7];
    const float* Wk  = (const float*)d_in[8];
    const float* bk  = (const float*)d_in[9];
    float* out = (float*)d_out;

    const int B = 65536, DIN = 512, H1 = 1024, H2 = 512;

    char* cur = (char*)d_ws;
    auto carve = [&](size_t bytes) {
        char* p = cur;
        cur += (bytes + 255) & ~(size_t)255;
        return p;
    };
    float*  partials = (float*)carve(4096 * 4);
    float*  bhead    = (float*)carve(512);
    bf16_t* W1T      = (bf16_t*)carve((size_t)H1 * DIN * 2);
    bf16_t* W2T      = (bf16_t*)carve((size_t)H2 * H1 * 2);
    bf16_t* WhT      = (bf16_t*)carve((size_t)128 * H2 * 2);

    // per-row slice bytes: xb 1024 + h1 2048 + h2 1024 = 4096
    size_t used = (size_t)(cur - (char*)d_ws);
    size_t avail = (ws_size > used + 1024) ? (ws_size - used - 1024) : 0;
    int SLICE = 2048;
    const int cands[6] = {65536, 32768, 16384, 8192, 4096, 2048};
    for (int ci = 0; ci < 6; ++ci) {
        if ((size_t)cands[ci] * 4096 <= avail) { SLICE = cands[ci]; break; }
    }
    bf16_t* xb = (bf16_t*)carve((size_t)SLICE * DIN * 2);
    bf16_t* h1 = (bf16_t*)carve((size_t)SLICE * H1 * 2);
    bf16_t* h2 = (bf16_t*)carve((size_t)SLICE * H2 * 2);

    transpose_w<<<(H1 * DIN + 255) / 256, 256, 0, stream>>>(W1, W1T, 9,  H1, H1 * DIN);
    transpose_w<<<(H2 * H1 + 255) / 256, 256, 0, stream>>>(W2, W2T, 10, H2, H2 * H1);
    pack_head<<<256, 256, 0, stream>>>(Wf, bfv, Wk, bk, WhT, bhead);

    for (int r0 = 0; r0 < B; r0 += SLICE) {
        convert_x<<<SLICE / 4, 256, 0, stream>>>(x + (size_t)r0 * DIN, xb, SLICE * DIN / 8);
        gemm128<true><<<(SLICE / 128) * (H1 / 128), 256, 0, stream>>>(xb, W1T, b1, h1, H1, DIN, H1 / 128);
        gemm128<true><<<(SLICE / 128) * (H2 / 128), 256, 0, stream>>>(h1, W2T, b2, h2, H2, H1, H2 / 128);
        head_fused<<<SLICE / 128, 256, 0, stream>>>(h2, WhT, bhead, dat, out + 1, partials, H2, r0);
    }
    reduce_loss<<<1, 256, 0, stream>>>(partials, B / 128, out, 1.0f / B);
}

// Round 12
// 237.536 us; speedup vs baseline: 1.1646x; 1.1646x over previous
//
#include <hip/hip_runtime.h>
#include <cmath>

#define EPSV 1e-8f

typedef __bf16 bf16_t;
typedef __bf16 bf16x8 __attribute__((ext_vector_type(8)));
typedef __bf16 bf16x4 __attribute__((ext_vector_type(4)));
typedef float f32x4 __attribute__((ext_vector_type(4)));

__device__ __forceinline__ void gload16(const void* g, void* l) {
    __builtin_amdgcn_global_load_lds(
        (const __attribute__((address_space(1))) void*)g,
        (__attribute__((address_space(3))) void*)l, 16, 0, 0);
}

// Swizzled LDS half-tile: 256 rows x 32 k (bf16), 16 KB = 1024 16B-units.
__device__ __forceinline__ void qmap(int q, int& row, int& u) {
    int prow = q >> 3;
    int v = (q & 7) ^ (prow & 7);
    row = (prow << 1) | (v >> 2);
    u = v & 3;
}
__device__ __forceinline__ int lds_elem(int row, int u) {
    int prow = row >> 1;
    int v = ((row & 1) << 2) | u;
    return prow * 64 + ((v ^ (prow & 7)) << 3);   // bf16-element offset
}

// ---- 256x256 MFMA GEMM, BK=64 dbuf, 4-phase, REGISTER-PIPELINED operands --
// vs r10: af ping-pong (af0/af1) read ONE PHASE AHEAD of use, so each phase's
// MFMA cluster starts with operands already in VGPRs (ph2/ph4: zero wait;
// ph1/ph3: wait only on 4 bfr reads). Reads of tiles confirmed by an in-phase
// vmcnt are placed AFTER that vmcnt+barrier (ledger below).
// STAGE schedule + vmcnt ledger byte-identical to r10 (proven 5 rounds):
//   ph1 STAGE A1(t+1); ph2 STAGE B1(t+1), vmcnt(8) => A1(t),B1(t) valid;
//   ph3 STAGE A0(t+2); ph4 STAGE B0(t+2), vmcnt(8) => A0(t+1),B0(t+1) valid.
// Read placement: bfr(B0) @ph1-top (valid since kt-1 ph4); af1(A0[4:8]) @ph1;
//   af0(A1[0:4]) @ph2 AFTER vmcnt; bfr(B1),af1(A1[4:8]) @ph3 (valid since ph2);
//   af0(A0(t+1)[0:4]) @ph4 AFTER vmcnt. WAR on A1(t) region: overwritten at
//   kt+1 ph1 (buf c), reads done by kt ph3. All guarded by barriers.
template<bool RELU>
__global__ __launch_bounds__(512, 2) void gemm256(
    const bf16_t* __restrict__ A, const bf16_t* __restrict__ BT,
    const float* __restrict__ bias, bf16_t* __restrict__ C,
    int N, int K, int nbx)
{
    __shared__ bf16_t sm[2][2][2][8192];   // [buf][A/B][kslice][16KB] = 128 KB

    const int t    = threadIdx.x;
    const int lane = t & 63;
    const int w    = t >> 6;
    const int wr   = w >> 2;
    const int wc   = w & 3;
    const int r16  = lane & 15;
    const int u16  = lane >> 4;

    const int nwg = gridDim.x;
    int bid = blockIdx.x;
    int swz = ((nwg & 7) == 0) ? ((bid & 7) * (nwg >> 3) + (bid >> 3)) : bid;
    const int bx = swz % nbx, by = swz / nbx;
    const int m0 = by << 8, n0 = bx << 8;

    int r0, u0, r1, u1;
    qmap(t, r0, u0);
    qmap(t + 512, r1, u1);
    const bf16_t* gA0 = A  + (size_t)(m0 + r0) * K + (u0 << 3);
    const bf16_t* gA1 = A  + (size_t)(m0 + r1) * K + (u1 << 3);
    const bf16_t* gB0 = BT + (size_t)(n0 + r0) * K + (u0 << 3);
    const bf16_t* gB1 = BT + (size_t)(n0 + r1) * K + (u1 << 3);

    auto STAGE = [&](const bf16_t* g0, const bf16_t* g1, bf16_t* sl, int koff) {
        gload16(g0 + koff, sl + (w << 9));
        gload16(g1 + koff, sl + 4096 + (w << 9));
    };

    int aoff[8], boff[4];
#pragma unroll
    for (int i = 0; i < 8; ++i) aoff[i] = lds_elem((wr << 7) + (i << 4) + r16, u16);
#pragma unroll
    for (int j = 0; j < 4; ++j) boff[j] = lds_elem((wc << 6) + (j << 4) + r16, u16);

    f32x4 acc[8][4];
#pragma unroll
    for (int i = 0; i < 8; ++i)
#pragma unroll
        for (int j = 0; j < 4; ++j) acc[i][j] = (f32x4){0.f, 0.f, 0.f, 0.f};

    const int NT = K >> 6;

    // prologue: steady-state FIFO window = 6 pairs
    STAGE(gA0, gA1, &sm[0][0][0][0], 0);    // A0(0)
    STAGE(gB0, gB1, &sm[0][1][0][0], 0);    // B0(0)
    STAGE(gA0, gA1, &sm[0][0][1][0], 32);   // A1(0)
    STAGE(gB0, gB1, &sm[0][1][1][0], 32);   // B1(0)
    STAGE(gA0, gA1, &sm[1][0][0][0], 64);   // A0(1)
    STAGE(gB0, gB1, &sm[1][1][0][0], 64);   // B0(1)
    asm volatile("s_waitcnt vmcnt(8)" ::: "memory");   // A0(0),B0(0) landed
    __builtin_amdgcn_s_barrier();

    bf16x8 af0[4], af1[4], bfr[4];
    // pre-read: A0(0)[0:4] for first ph1's MFMA
#pragma unroll
    for (int i = 0; i < 4; ++i) af0[i] = *(const bf16x8*)(&sm[0][0][0][0] + aoff[i]);

    for (int kt = 0; kt < NT; ++kt) {
        const int c  = kt & 1;
        const int c1 = c ^ 1;
        const bool s12 = (kt + 1) < NT;
        const bool s34 = (kt + 2) < NT;
        const int k12 = ((kt + 1) << 6) + 32;
        const int k34 = (kt + 2) << 6;
        const bf16_t* sA0 = &sm[c][0][0][0];
        const bf16_t* sA1 = &sm[c][0][1][0];
        const bf16_t* sB0 = &sm[c][1][0][0];
        const bf16_t* sB1 = &sm[c][1][1][0];

        // ------------- phase 1: MFMA(B0, A0[0:4]) -------------
#pragma unroll
        for (int j = 0; j < 4; ++j) bfr[j] = *(const bf16x8*)(sB0 + boff[j]);
#pragma unroll
        for (int i = 0; i < 4; ++i) af1[i] = *(const bf16x8*)(sA0 + aoff[4 + i]);
        if (s12) STAGE(gA0, gA1, &sm[c1][0][1][0], k12);   // A1(t+1)
        __builtin_amdgcn_s_barrier();
        __builtin_amdgcn_s_setprio(1);
#pragma unroll
        for (int i = 0; i < 4; ++i)
#pragma unroll
            for (int j = 0; j < 4; ++j)
                acc[i][j] = __builtin_amdgcn_mfma_f32_16x16x32_bf16(bfr[j], af0[i], acc[i][j], 0, 0, 0);
        __builtin_amdgcn_s_setprio(0);
        __builtin_amdgcn_s_barrier();

        // ------------- phase 2: MFMA(B0, A0[4:8]) -------------
        if (s12) STAGE(gB0, gB1, &sm[c1][1][1][0], k12);   // B1(t+1)
        if (s12) asm volatile("s_waitcnt vmcnt(8)" ::: "memory");  // A1(t),B1(t) in
        else     asm volatile("s_waitcnt vmcnt(0)" ::: "memory");
        __builtin_amdgcn_s_barrier();
#pragma unroll
        for (int i = 0; i < 4; ++i) af0[i] = *(const bf16x8*)(sA1 + aoff[i]);  // A1[0:4] for ph3
        __builtin_amdgcn_s_setprio(1);
#pragma unroll
        for (int i = 0; i < 4; ++i)
#pragma unroll
            for (int j = 0; j < 4; ++j)
                acc[4 + i][j] = __builtin_amdgcn_mfma_f32_16x16x32_bf16(bfr[j], af1[i], acc[4 + i][j], 0, 0, 0);
        __builtin_amdgcn_s_setprio(0);
        __builtin_amdgcn_s_barrier();

        // ------------- phase 3: MFMA(B1, A1[0:4]) -------------
#pragma unroll
        for (int j = 0; j < 4; ++j) bfr[j] = *(const bf16x8*)(sB1 + boff[j]);
#pragma unroll
        for (int i = 0; i < 4; ++i) af1[i] = *(const bf16x8*)(sA1 + aoff[4 + i]);
        if (s34) STAGE(gA0, gA1, &sm[c][0][0][0], k34);    // A0(t+2)
        __builtin_amdgcn_s_barrier();
        __builtin_amdgcn_s_setprio(1);
#pragma unroll
        for (int i = 0; i < 4; ++i)
#pragma unroll
            for (int j = 0; j < 4; ++j)
                acc[i][j] = __builtin_amdgcn_mfma_f32_16x16x32_bf16(bfr[j], af0[i], acc[i][j], 0, 0, 0);
        __builtin_amdgcn_s_setprio(0);
        __builtin_amdgcn_s_barrier();

        // ------------- phase 4: MFMA(B1, A1[4:8]) -------------
        if (s34) STAGE(gB0, gB1, &sm[c][1][0][0], k34);    // B0(t+2)
        if (s34)      asm volatile("s_waitcnt vmcnt(8)" ::: "memory");  // A0/B0(t+1) in
        else if (s12) asm volatile("s_waitcnt vmcnt(4)" ::: "memory");
        __builtin_amdgcn_s_barrier();
        if (s12) {
#pragma unroll
            for (int i = 0; i < 4; ++i)
                af0[i] = *(const bf16x8*)(&sm[c1][0][0][0] + aoff[i]);  // A0(t+1)[0:4] for next ph1
        }
        __builtin_amdgcn_s_setprio(1);
#pragma unroll
        for (int i = 0; i < 4; ++i)
#pragma unroll
            for (int j = 0; j < 4; ++j)
                acc[4 + i][j] = __builtin_amdgcn_mfma_f32_16x16x32_bf16(bfr[j], af1[i], acc[4 + i][j], 0, 0, 0);
        __builtin_amdgcn_s_setprio(0);
        __builtin_amdgcn_s_barrier();
    }

    __syncthreads();   // full drain before LDS reuse

    // ------- epilogue: bias+relu, LDS-staged transpose, coalesced stores ----
    char* eb = (char*)&sm[0][0][0][0];  // 128 KB = 256 x 512B rows
    const int mBb = (wr << 7) + r16;
    const int nBb = (wc << 6) + (u16 << 2);
#pragma unroll
    for (int i = 0; i < 8; ++i) {
        const int m = mBb + (i << 4);
        const int xm = (m & 15) << 4;
#pragma unroll
        for (int j = 0; j < 4; ++j) {
            const int nl = nBb + (j << 4);
            f32x4 bv = *(const f32x4*)(bias + n0 + nl);
            bf16x4 pk;
#pragma unroll
            for (int r = 0; r < 4; ++r) {
                float v = acc[i][j][r] + bv[r];
                if (RELU) v = fmaxf(v, 0.f);
                pk[r] = (bf16_t)v;
            }
            *(bf16x4*)(eb + m * 512 + ((nl << 1) ^ xm)) = pk;
        }
    }
    __syncthreads();
    const int cc = t & 31;
    const int rr = t >> 5;
#pragma unroll
    for (int rp = 0; rp < 16; ++rp) {
        const int m = (rp << 4) + rr;
        bf16x8 v = *(const bf16x8*)(eb + m * 512 + (((cc << 4) ^ ((m & 15) << 4)) & 511));
        *(bf16x8*)(C + (size_t)(m0 + m) * N + n0 + (cc << 3)) = v;
    }
}

// ---- fused head: hd = h2 @ Whead + bhead (128x128 tile in LDS), then ------
// probability pipeline + per-block loss partial. One block per 128 rows.
__global__ __launch_bounds__(256) void head_fused(
    const bf16_t* __restrict__ A, const bf16_t* __restrict__ BT,
    const float* __restrict__ bias, const int* __restrict__ data,
    float* __restrict__ probs_out, float* __restrict__ partials,
    int K, int row0)
{
    __shared__ __align__(16) bf16_t As[128 * 32];
    __shared__ __align__(16) bf16_t Bs[128 * 32];
    __shared__ float hdl[128 * 128];

    const int t    = threadIdx.x;
    const int lane = t & 63;
    const int w    = t >> 6;
    const int wm   = (w >> 1) << 6;
    const int wn   = (w & 1) << 6;
    const int m0l  = blockIdx.x << 7;

    const int srow  = t >> 2;
    const int skoff = (t & 3) << 3;

    const bf16_t* Ap = A  + (size_t)(m0l + srow) * K + skoff;
    const bf16_t* Bp = BT + (size_t)srow * K + skoff;
    const size_t rstep = (size_t)64 * K;

    bf16_t* lA0 = As + ((w << 6)      ) * 8;
    bf16_t* lA1 = As + ((w << 6) + 256) * 8;
    bf16_t* lB0 = Bs + ((w << 6)      ) * 8;
    bf16_t* lB1 = Bs + ((w << 6) + 256) * 8;

    f32x4 acc[4][4];
#pragma unroll
    for (int i = 0; i < 4; ++i)
#pragma unroll
        for (int j = 0; j < 4; ++j) acc[i][j] = (f32x4){0.f, 0.f, 0.f, 0.f};

    const int r16  = lane & 15;
    const int u16  = lane >> 4;
    const int kblk = u16 << 3;

    for (int k0 = 0; k0 < K; k0 += 32) {
        __syncthreads();
        gload16(Ap + k0,         lA0);
        gload16(Ap + rstep + k0, lA1);
        gload16(Bp + k0,         lB0);
        gload16(Bp + rstep + k0, lB1);
        __syncthreads();

        bf16x8 af[4], bfr[4];
#pragma unroll
        for (int i = 0; i < 4; ++i) {
            af[i]  = *(const bf16x8*)&As[(wm + (i << 4) + r16) * 32 + kblk];
            bfr[i] = *(const bf16x8*)&Bs[(wn + (i << 4) + r16) * 32 + kblk];
        }
#pragma unroll
        for (int i = 0; i < 4; ++i)
#pragma unroll
            for (int j = 0; j < 4; ++j)
                acc[i][j] = __builtin_amdgcn_mfma_f32_16x16x32_bf16(af[i], bfr[j], acc[i][j], 0, 0, 0);
    }

    // hd tile -> LDS (f32), bias added
#pragma unroll
    for (int j = 0; j < 4; ++j) {
        const int col = wn + (j << 4) + r16;
        const float bv = bias[col];
#pragma unroll
        for (int i = 0; i < 4; ++i) {
            const int rb = wm + (i << 4) + (u16 << 2);
#pragma unroll
            for (int r = 0; r < 4; ++r)
                hdl[(rb + r) * 128 + col] = acc[i][j][r] + bv;
        }
    }
    __syncthreads();

    // probability pipeline: 8 (row,item) pairs per thread
    float lsum = 0.f;
    const int item = t & 15;
    const int cp   = 4 + (item & 3);
#pragma unroll
    for (int p = 0; p < 8; ++p) {
        const int row = (p << 4) + (t >> 4);
        const float* h = hdl + row * 128;
        const size_t grow = (size_t)row0 + m0l + row;

        const float f = h[item];
        float cumP[7];
        float cum = 0.f;
#pragma unroll
        for (int c = 0; c < 7; ++c) {
            if (c < cp) {
                float e = fmaxf(expf(h[16 + item * 7 + c]), EPSV);
                cum += e;
                float s = 1.f / (1.f + expf(f - cum));
                cumP[c] = fminf(fmaxf(s, EPSV), 1.f - EPSV);
            } else {
                cumP[c] = 0.f;
            }
        }
        float probs[8];
#pragma unroll
        for (int k = 0; k < 8; ++k) {
            float v;
            if (k < cp)       v = (k == 0) ? cumP[0] : (cumP[k] - cumP[k - 1]);
            else if (k == cp) v = 1.f - cumP[cp - 1];
            else              v = 1.f;
            probs[k] = fminf(fmaxf(v, EPSV), 1.f - EPSV);
        }
        float* dst = probs_out + (grow * 16 + item) * 8;
#pragma unroll
        for (int k = 0; k < 8; ++k) dst[k] = probs[k];

        const int d = data[grow * 16 + item];
        float g = probs[0];
#pragma unroll
        for (int k = 1; k < 8; ++k) g = (d == k) ? probs[k] : g;
        lsum += -logf(g);
    }

    __syncthreads();
    float* red = (float*)As;
    red[t] = lsum;
    __syncthreads();
#pragma unroll
    for (int s2 = 128; s2 > 0; s2 >>= 1) {
        if (t < s2) red[t] += red[t + s2];
        __syncthreads();
    }
    if (t == 0) partials[(row0 >> 7) + blockIdx.x] = red[0];
}

// ---------------- fp32 -> bf16 conversion (8 elems/thread) ----------------
__global__ __launch_bounds__(256) void convert_x(
    const float* __restrict__ in, bf16_t* __restrict__ out, int n8)
{
    int i = blockIdx.x * 256 + threadIdx.x;
    if (i >= n8) return;
    const float4* p = (const float4*)in;
    float4 a = p[2 * i], b = p[2 * i + 1];
    bf16x8 v;
    v[0] = (bf16_t)a.x; v[1] = (bf16_t)a.y; v[2] = (bf16_t)a.z; v[3] = (bf16_t)a.w;
    v[4] = (bf16_t)b.x; v[5] = (bf16_t)b.y; v[6] = (bf16_t)b.z; v[7] = (bf16_t)b.w;
    ((bf16x8*)out)[i] = v;
}

// ---------------- transpose weight K x N fp32 -> N x K bf16 ----------------
__global__ __launch_bounds__(256) void transpose_w(
    const float* __restrict__ in, bf16_t* __restrict__ out,
    int kshift, int N, int total)
{
    int idx = blockIdx.x * 256 + threadIdx.x;
    if (idx >= total) return;
    int n = idx >> kshift;
    int k = idx & ((1 << kshift) - 1);
    out[idx] = (bf16_t)in[(size_t)k * N + n];
}

// ---------------- pack head: WheadT (128 x 512) bf16 + bhead (128) f32 -----
__global__ __launch_bounds__(256) void pack_head(
    const float* __restrict__ Wf, const float* __restrict__ bfv,
    const float* __restrict__ Wk, const float* __restrict__ bk,
    bf16_t* __restrict__ WhT, float* __restrict__ bhead)
{
    int idx = blockIdx.x * 256 + threadIdx.x;  // 0..65535
    int n = idx >> 9;
    int k = idx & 511;
    float v;
    if (n < 16) {
        v = Wf[k * 16 + n];
    } else {
        int m = n - 16;
        int i = m / 7, c = m % 7;
        v = Wk[(size_t)i * 3584 + (size_t)k * 7 + c];
    }
    WhT[idx] = (bf16_t)v;
    if (idx < 128) bhead[idx] = (idx < 16) ? bfv[idx] : bk[idx - 16];
}

__global__ __launch_bounds__(256) void reduce_loss(
    const float* __restrict__ partials, int n, float* __restrict__ out, float scale)
{
    __shared__ float red[256];
    float s = 0.f;
    for (int i = threadIdx.x; i < n; i += 256) s += partials[i];
    red[threadIdx.x] = s;
    __syncthreads();
    for (int k = 128; k > 0; k >>= 1) {
        if (threadIdx.x < k) red[threadIdx.x] += red[threadIdx.x + k];
        __syncthreads();
    }
    if (threadIdx.x == 0) out[0] = red[0] * scale;
}

extern "C" void kernel_launch(void* const* d_in, const int* in_sizes, int n_in,
                              void* d_out, int out_size, void* d_ws, size_t ws_size,
                              hipStream_t stream)
{
    const float* x   = (const float*)d_in[0];
    const int*   dat = (const int*)d_in[1];
    const float* W1  = (const float*)d_in[2];
    const float* b1  = (const float*)d_in[3];
    const float* W2  = (const float*)d_in[4];
    const float* b2  = (const float*)d_in[5];
    const float* Wf  = (const float*)d_in[6];
    const float* bfv = (const float*)d_in[7];
    const float* Wk  = (const float*)d_in[8];
    const float* bk  = (const float*)d_in[9];
    float* out = (float*)d_out;

    const int B = 65536, DIN = 512, H1 = 1024, H2 = 512;

    char* cur = (char*)d_ws;
    auto carve = [&](size_t bytes) {
        char* p = cur;
        cur += (bytes + 255) & ~(size_t)255;
        return p;
    };
    float*  partials = (float*)carve(4096 * 4);
    float*  bhead    = (float*)carve(512);
    bf16_t* W1T      = (bf16_t*)carve((size_t)H1 * DIN * 2);
    bf16_t* W2T      = (bf16_t*)carve((size_t)H2 * H1 * 2);
    bf16_t* WhT      = (bf16_t*)carve((size_t)128 * H2 * 2);

    // per-row slice bytes: xb 1024 + h1 2048 + h2 1024 = 4096
    size_t used = (size_t)(cur - (char*)d_ws);
    size_t avail = (ws_size > used + 1024) ? (ws_size - used - 1024) : 0;
    int SLICE = 2048;
    const int cands[6] = {65536, 32768, 16384, 8192, 4096, 2048};
    for (int ci = 0; ci < 6; ++ci) {
        if ((size_t)cands[ci] * 4096 <= avail) { SLICE = cands[ci]; break; }
    }
    bf16_t* xb = (bf16_t*)carve((size_t)SLICE * DIN * 2);
    bf16_t* h1 = (bf16_t*)carve((size_t)SLICE * H1 * 2);
    bf16_t* h2 = (bf16_t*)carve((size_t)SLICE * H2 * 2);

    transpose_w<<<(H1 * DIN + 255) / 256, 256, 0, stream>>>(W1, W1T, 9,  H1, H1 * DIN);
    transpose_w<<<(H2 * H1 + 255) / 256, 256, 0, stream>>>(W2, W2T, 10, H2, H2 * H1);
    pack_head<<<256, 256, 0, stream>>>(Wf, bfv, Wk, bk, WhT, bhead);

    for (int r0 = 0; r0 < B; r0 += SLICE) {
        convert_x<<<SLICE / 4, 256, 0, stream>>>(x + (size_t)r0 * DIN, xb, SLICE * DIN / 8);
        gemm256<true><<<(SLICE / 256) * (H1 / 256), 512, 0, stream>>>(xb, W1T, b1, h1, H1, DIN, H1 / 256);
        gemm256<true><<<(SLICE / 256) * (H2 / 256), 512, 0, stream>>>(h1, W2T, b2, h2, H2, H1, H2 / 256);
        head_fused<<<SLICE / 128, 256, 0, stream>>>(h2, WhT, bhead, dat, out + 1, partials, H2, r0);
    }
    reduce_loss<<<1, 256, 0, stream>>>(partials, B / 128, out, 1.0f / B);
}